// Round 4
// baseline (707.072 us; speedup 1.0000x reference)
//
#include <hip/hip_runtime.h>

// db4 synthesis filters. g1[j] = (-1)^j * g0[7-j].
__device__ constexpr float G0[8] = {
    0.23037781330885523f,  0.7148465705525415f,  0.6308807679295904f,  -0.02798376941698385f,
    -0.18703481171888114f, 0.030841381835986965f, 0.032883011666982945f, -0.010597401784997278f};
__device__ constexpr float G1[8] = {
    -0.010597401784997278f, -0.032883011666982945f, 0.030841381835986965f, 0.18703481171888114f,
    -0.02798376941698385f,  -0.6308807679295904f,   0.7148465705525415f,  -0.23037781330885523f};

// One level of 3D inverse db4 DWT as a direct gather (tensor-product expansion).
// low:(16,n,n,n) highs:(16,7,n,n,n) -> out:(16,N,N,N), N=2n-6.
//
// out[gz][gy][gx] = sum_{band} sum_{mz,my,mx in 0..3}
//     src_band[(gz>>1)+3-mz][(gy>>1)+3-my][(gx>>1)+3-mx]
//     * Wz[(gz&1)+2mz] * Wy[(gy&1)+2my] * Wx[(gx&1)+2mx]
// band bits: bit0=x, bit1=y, bit2=z (G1 if set).
//
// R3 change (issue/latency theory): each thread computes a 4x4x2 output tile
// (2x2 ublocks in z,y; full parity everywhere). Per band it loads a 5x5 row
// footprint (25 rows of 4 floats) shared by all 32 outputs, and factorizes the
// reduction: x-dots d[du][px] -> y-contract ey[yo][px] -> z-accumulate into
// acc[zo][yo][px]. Per-output: 6.25 row-loads (was 16) and ~122 FP ops
// (was 256). All arrays statically indexed under full unroll (no scratch).
//
// Odd-H handling: H=63/33 is odd, so the last z/y ublock-pair is truncated.
// Reads at dv==4 / du==4 can hit index n (once, at the truncated edge) -> clamp
// to n-1; the polluted values only feed the second-ublock outputs (zo>=2 /
// yo>=2), which are not stored there. Stores are guarded by z1ok/y1ok.
__global__ __launch_bounds__(256) void idwt3_gather32(const float* __restrict__ low,
                                                      const float* __restrict__ highs,
                                                      float* __restrict__ out,
                                                      int n, int N) {
  const int b = blockIdx.y;
  const long n3 = (long)n * n * n;
  const int H = N >> 1;                 // output ublocks per axis
  const int Hp = (H + 1) >> 1;          // ublock-pairs per axis (y,z)
  const int nthreads = H * Hp * Hp;
  const int q = blockIdx.x * 256 + threadIdx.x;
  if (q >= nthreads) return;
  const int ux = q % H;
  const int t1 = q / H;
  const int yb0 = (t1 % Hp) << 1;       // first y-ublock of the pair
  const int zb0 = (t1 / Hp) << 1;       // first z-ublock of the pair
  const bool y1ok = (yb0 + 1) < H;
  const bool z1ok = (zb0 + 1) < H;

  float acc[4][4][2] = {};              // [zo][yo][px]; gz=2*zb0+zo, gy=2*yb0+yo

#pragma unroll
  for (int band = 0; band < 8; ++band) {
    const float* src = (band == 0) ? (low + (long)b * n3)
                                   : (highs + ((long)b * 7 + (band - 1)) * n3);
    const float* Gx = (band & 1) ? G1 : G0;   // folds at compile time
    const float* Gy = (band & 2) ? G1 : G0;
    const float* Gz = (band & 4) ? G1 : G0;
#pragma unroll
    for (int dv = 0; dv < 5; ++dv) {
      int v = zb0 + dv;
      if (dv == 4) v = min(v, n - 1);         // truncated-edge clamp (see above)
      const float* vbase = src + (long)v * n * n + ux;

      // x-dots for the 5 source y-rows of this z-slice.
      float d[5][2];                          // [du][px]
#pragma unroll
      for (int du = 0; du < 5; ++du) {
        int u = yb0 + du;
        if (du == 4) u = min(u, n - 1);
        const float* row = vbase + (long)u * n;
        const float r0 = row[0], r1 = row[1], r2 = row[2], r3 = row[3];
        // x: input idx ux+3-mx pairs with Wx[px+2mx] -> row[3-mx]*Gx[px+2mx]
        d[du][0] = r3 * Gx[0] + r2 * Gx[2] + r1 * Gx[4] + r0 * Gx[6];
        d[du][1] = r3 * Gx[1] + r2 * Gx[3] + r1 * Gx[5] + r0 * Gx[7];
      }

      // y-contract: ey[yo][px], yo=(yblock<<1)|py ordered as gy=2*yb0+yo.
      float ey[4][2];
#pragma unroll
      for (int yo = 0; yo < 4; ++yo) {
        const int py = yo & 1, yb = yo >> 1;
#pragma unroll
        for (int px = 0; px < 2; ++px) {
          float s = 0.0f;
#pragma unroll
          for (int du = yb; du < yb + 4; ++du)   // my = yb+3-du
            s = fmaf(d[du][px], Gy[py + 2 * (yb + 3 - du)], s);
          ey[yo][px] = s;
        }
      }

      // z-accumulate: this z-slice (dv) feeds zo where mz = (zo>>1)+3-dv in [0,3].
#pragma unroll
      for (int zo = 0; zo < 4; ++zo) {
        const int pz = zo & 1, zb = zo >> 1;
        const int mz = zb + 3 - dv;
        if (mz >= 0 && mz <= 3) {
          const float w = Gz[pz + 2 * mz];
#pragma unroll
          for (int yo = 0; yo < 4; ++yo)
#pragma unroll
            for (int px = 0; px < 2; ++px)
              acc[zo][yo][px] = fmaf(ey[yo][px], w, acc[zo][yo][px]);
        }
      }
    }
  }

  const long N3 = (long)N * N * N;
  float* obase = out + (long)b * N3 + 2 * ux;
#pragma unroll
  for (int zo = 0; zo < 4; ++zo) {
    if (zo >= 2 && !z1ok) continue;
    const int gz = 2 * zb0 + zo;
#pragma unroll
    for (int yo = 0; yo < 4; ++yo) {
      if (yo >= 2 && !y1ok) continue;
      const int gy = 2 * yb0 + yo;
      // 2*ux is even -> 8B-aligned float2 store.
      float2 vv = make_float2(acc[zo][yo][0], acc[zo][yo][1]);
      *reinterpret_cast<float2*>(obase + ((long)gz * N + gy) * N) = vv;
    }
  }
}

extern "C" void kernel_launch(void* const* d_in, const int* in_sizes, int n_in,
                              void* d_out, int out_size, void* d_ws, size_t ws_size,
                              hipStream_t stream) {
  // Identify inputs BY SIZE (element counts — confirmed in prior session):
  //   yl  (2,8,36^3)    =   746,496
  //   yh0 (2,8,7,66^3)  = 32,199,552
  //   yh1 (2,8,7,36^3)  =  5,225,472
  const float* yl  = nullptr;
  const float* yh0 = nullptr;
  const float* yh1 = nullptr;
  for (int i = 0; i < n_in; ++i) {
    if (in_sizes[i] == 746496)        yl  = (const float*)d_in[i];
    else if (in_sizes[i] == 32199552) yh0 = (const float*)d_in[i];
    else if (in_sizes[i] == 5225472)  yh1 = (const float*)d_in[i];
  }
  if (!yl || !yh0 || !yh1) {
    yl  = (const float*)d_in[0];
    yh0 = (const float*)d_in[1];
    yh1 = (const float*)d_in[2];
  }
  float* out = (float*)d_out;      // fp32 output (verified prior session)
  float* ll  = (float*)d_ws;       // (16,66^3) fp32 = 18.4 MB inter-level buffer

  // Level 1: (36 -> 66). H=33, Hp=17 -> 33*17*17 = 9537 threads/vol -> 38 blocks.
  idwt3_gather32<<<dim3(38, 16), 256, 0, stream>>>(yl, yh1, ll, 36, 66);

  // Level 2: (66 -> 126). H=63, Hp=32 -> 63*32*32 = 64512 threads/vol -> 252 blocks.
  idwt3_gather32<<<dim3(252, 16), 256, 0, stream>>>(ll, yh0, out, 66, 126);
}

// Round 8
// 526.177 us; speedup vs baseline: 1.3438x; 1.3438x over previous
//
#include <hip/hip_runtime.h>

// db4 synthesis filters. g1[j] = (-1)^j * g0[7-j].
__device__ constexpr float G0[8] = {
    0.23037781330885523f,  0.7148465705525415f,  0.6308807679295904f,  -0.02798376941698385f,
    -0.18703481171888114f, 0.030841381835986965f, 0.032883011666982945f, -0.010597401784997278f};
__device__ constexpr float G1[8] = {
    -0.010597401784997278f, -0.032883011666982945f, 0.030841381835986965f, 0.18703481171888114f,
    -0.02798376941698385f,  -0.6308807679295904f,   0.7148465705525415f,  -0.23037781330885523f};

// One level of 3D inverse db4 DWT as a direct gather (tensor-product expansion).
// low:(16,n,n,n) highs:(16,7,n,n,n) -> out:(16,N,N,N), N=2n-6.
//
// out[gz][gy][gx] = sum_{band} sum_{mz,my,mx in 0..3}
//     src_band[(gz>>1)+3-mz][(gy>>1)+3-my][(gx>>1)+3-mx]
//     * Wz[(gz&1)+2mz] * Wy[(gy&1)+2my] * Wx[(gx&1)+2mx]
// band bits: bit0=x, bit1=y, bit2=z (G1 if set).
//
// R4: midpoint between R0 (2x2x2 tile, 339us, VGPR 36, occ 66%) and R3
// (4x4x2 tile, 460us, VGPR 252, occ 11% -- register blowup). Tile = 4x2x2
// (z-ublock PAIR only): acc[4][2][2] = 16 regs. Factorized reduction:
// x-dots d[4][2] per z-slice -> y-contract ey[2][2] -> z-accumulate.
// Per band: 5 slices x 4 rows = 20 row-loads for 16 outputs (1.25 rows/out
// vs R0's 2.0), 304 FP ops (19/out vs R0's 32).
// The band loop is deliberately NOT unrolled (#pragma unroll 1): this caps
// load-hoisting live ranges (R3's failure mode). Weights become uniform
// s_loads -- cheap; the factorized form needs no weight cross-products.
//
// Odd-H handling (z only; y/x are uncoarsened and provably in-bounds):
// H=63/33 odd -> last z-pair truncated. dv==4 can read slice n at the
// truncated edge -> clamp to n-1; polluted values only feed zo>=2 outputs,
// which are not stored there (z1ok guard).
__global__ __launch_bounds__(256) void idwt3_gather16(const float* __restrict__ low,
                                                      const float* __restrict__ highs,
                                                      float* __restrict__ out,
                                                      int n, int N) {
  const int b = blockIdx.y;
  const long n3 = (long)n * n * n;
  const int H = N >> 1;                  // output ublocks per axis
  const int Hp = (H + 1) >> 1;           // z ublock-pairs
  const int nthreads = H * H * Hp;
  const int q = blockIdx.x * 256 + threadIdx.x;
  if (q >= nthreads) return;
  const int ux = q % H;
  const int t1 = q / H;
  const int uy = t1 % H;
  const int zb0 = (t1 / H) << 1;         // first z-ublock of the pair
  const bool z1ok = (zb0 + 1) < H;

  const int nn = n * n;
  float acc[4][2][2] = {};               // [zo][py][px]; gz=2*zb0+zo, gy=2*uy+py

#pragma unroll 1
  for (int band = 0; band < 8; ++band) {
    const float* src = (band == 0) ? (low + (long)b * n3)
                                   : (highs + ((long)b * 7 + (band - 1)) * n3);
    const float* Gx = (band & 1) ? G1 : G0;   // uniform -> scalar loads
    const float* Gy = (band & 2) ? G1 : G0;
    const float* Gz = (band & 4) ? G1 : G0;
#pragma unroll
    for (int dv = 0; dv < 5; ++dv) {
      int v = zb0 + dv;
      if (dv == 4) v = min(v, n - 1);    // truncated-edge clamp (see above)
      const float* sbase = src + (long)v * nn + (long)uy * n + ux;

      // x-dots for the 4 source y-rows of this z-slice (u = uy+du, my = 3-du).
      float d[4][2];                     // [du][px]
#pragma unroll
      for (int du = 0; du < 4; ++du) {
        const float* row = sbase + du * n;
        const float r0 = row[0], r1 = row[1], r2 = row[2], r3 = row[3];
        // x: src idx ux+3-mx pairs with Wx[px+2mx] -> row[3-mx]*Gx[px+2mx]
        d[du][0] = r3 * Gx[0] + r2 * Gx[2] + r1 * Gx[4] + r0 * Gx[6];
        d[du][1] = r3 * Gx[1] + r2 * Gx[3] + r1 * Gx[5] + r0 * Gx[7];
      }

      // y-contract: ey[py][px] = sum_du d[du][px] * Gy[py + 2*(3-du)]
      float ey[2][2];
#pragma unroll
      for (int py = 0; py < 2; ++py) {
#pragma unroll
        for (int px = 0; px < 2; ++px) {
          float s = d[0][px] * Gy[py + 6];
          s = fmaf(d[1][px], Gy[py + 4], s);
          s = fmaf(d[2][px], Gy[py + 2], s);
          s = fmaf(d[3][px], Gy[py + 0], s);
          ey[py][px] = s;
        }
      }

      // z-accumulate: slice dv feeds zo where mz = (zo>>1)+3-dv in [0,3].
      // (dv, zo unrolled -> guard and Gz index fold at compile time)
#pragma unroll
      for (int zo = 0; zo < 4; ++zo) {
        const int pz = zo & 1, zb = zo >> 1;
        const int mz = zb + 3 - dv;
        if (mz >= 0 && mz <= 3) {
          const float w = Gz[pz + 2 * mz];
#pragma unroll
          for (int py = 0; py < 2; ++py)
#pragma unroll
            for (int px = 0; px < 2; ++px)
              acc[zo][py][px] = fmaf(ey[py][px], w, acc[zo][py][px]);
        }
      }
    }
  }

  const long N3 = (long)N * N * N;
  float* obase = out + (long)b * N3 + 2 * ux;
#pragma unroll
  for (int zo = 0; zo < 4; ++zo) {
    if (zo >= 2 && !z1ok) continue;
    const int gz = 2 * zb0 + zo;
#pragma unroll
    for (int py = 0; py < 2; ++py) {
      const int gy = 2 * uy + py;
      // 2*ux is even -> 8B-aligned float2 store.
      float2 vv = make_float2(acc[zo][py][0], acc[zo][py][1]);
      *reinterpret_cast<float2*>(obase + ((long)gz * N + gy) * N) = vv;
    }
  }
}

extern "C" void kernel_launch(void* const* d_in, const int* in_sizes, int n_in,
                              void* d_out, int out_size, void* d_ws, size_t ws_size,
                              hipStream_t stream) {
  // Identify inputs BY SIZE (element counts — confirmed in prior session):
  //   yl  (2,8,36^3)    =   746,496
  //   yh0 (2,8,7,66^3)  = 32,199,552
  //   yh1 (2,8,7,36^3)  =  5,225,472
  const float* yl  = nullptr;
  const float* yh0 = nullptr;
  const float* yh1 = nullptr;
  for (int i = 0; i < n_in; ++i) {
    if (in_sizes[i] == 746496)        yl  = (const float*)d_in[i];
    else if (in_sizes[i] == 32199552) yh0 = (const float*)d_in[i];
    else if (in_sizes[i] == 5225472)  yh1 = (const float*)d_in[i];
  }
  if (!yl || !yh0 || !yh1) {
    yl  = (const float*)d_in[0];
    yh0 = (const float*)d_in[1];
    yh1 = (const float*)d_in[2];
  }
  float* out = (float*)d_out;      // fp32 output (verified prior session)
  float* ll  = (float*)d_ws;       // (16,66^3) fp32 = 18.4 MB inter-level buffer

  // Level 1: (36 -> 66). H=33, Hp=17 -> 33*33*17 = 18513 threads/vol -> 73 blocks.
  idwt3_gather16<<<dim3(73, 16), 256, 0, stream>>>(yl, yh1, ll, 36, 66);

  // Level 2: (66 -> 126). H=63, Hp=32 -> 63*63*32 = 127008 threads/vol -> 497 blocks.
  idwt3_gather16<<<dim3(497, 16), 256, 0, stream>>>(ll, yh0, out, 66, 126);
}

// Round 9
// 516.557 us; speedup vs baseline: 1.3688x; 1.0186x over previous
//
#include <hip/hip_runtime.h>

// db4 synthesis filters. g1[j] = (-1)^j * g0[7-j].
__device__ constexpr float G0[8] = {
    0.23037781330885523f,  0.7148465705525415f,  0.6308807679295904f,  -0.02798376941698385f,
    -0.18703481171888114f, 0.030841381835986965f, 0.032883011666982945f, -0.010597401784997278f};
__device__ constexpr float G1[8] = {
    -0.010597401784997278f, -0.032883011666982945f, 0.030841381835986965f, 0.18703481171888114f,
    -0.02798376941698385f,  -0.6308807679295904f,   0.7148465705525415f,  -0.23037781330885523f};

// One level of 3D inverse db4 DWT, LDS-staged (R8).
// out[gz][gy][gx] = sum_band sum_{mz,my,mx} src_band[(gz>>1)+3-mz][..][..] * W-products
// band bits: bit0=x (G1 if set), bit1=y, bit2=z.
//
// R4 was latency-bound (occ 44%, VALUBusy 30%, no resource cap): per-band
// dependent global gathers stall ~200-900cy with ~3.5 waves/SIMD. R8 stages
// each band's source slab into LDS with a 1-band-deep pipeline (T14 split:
// issue loads -> compute current band -> ds_write after barrier), converting
// latency-bound gathers into conflict-free LDS reads and cutting global read
// redundancy ~9x.
//
// Block tile: z-pair (4 z-outputs) x WY y-ublocks x full x. Slab per band:
// 5 z-slices, each a CONTIGUOUS global run of (WY+3) rows x n floats,
// staged as float4 (chunk bases provably %4==0). Overrun rows (y-edge tiles,
// z-clamped slices) read in-bounds garbage that only feeds unstored outputs;
// a per-float4 clamp to the volume end (n3/4-1) prevents buffer OOB (no
// straddling float4 exists since bases and n3 are %4==0).
template <int n, int WY>
__global__ __launch_bounds__(256) void idwt3_lds(const float* __restrict__ low,
                                                 const float* __restrict__ highs,
                                                 float* __restrict__ out) {
  constexpr int N = 2 * n - 6;
  constexpr int H = N / 2;                    // output ublocks per axis (n-3)
  constexpr int ROWS = WY + 3;                // slab rows per z-slice
  constexpr int REAL4 = (ROWS * n + 3) / 4;   // staged float4s per z-chunk
  constexpr int CH = 4 * REAL4;               // chunk stride in floats
  constexpr int TOT4 = 5 * REAL4;             // float4s per band slab
  constexpr int K = (TOT4 + 255) / 256;       // staging iters per thread
  constexpr long n3 = (long)n * n * n;
  constexpr int n3_4 = (int)(n3 / 4);

  __shared__ __align__(16) float slab[5 * CH];

  const int tid = threadIdx.x;
  const int zb0 = blockIdx.x * 2;             // first z-ublock of the pair
  const int yb0 = blockIdx.y * WY;            // first y-ublock of the tile
  const int b = blockIdx.z;
  const int ux = tid % H;
  const int ty = tid / H;                     // y-ublock within tile (if < WY)
  const bool z1ok = (zb0 + 1) < H;

  const float* const lowv = low + (long)b * n3;
  const float* const highv = highs + (long)b * 7 * n3;

  float4 st[K];                               // in-flight staged data (static idx)

  // Issue the global float4 loads for one band's slab into st[].
  auto stage_load = [&](int band) {
    const float* src = (band == 0) ? lowv : (highv + (long)(band - 1) * n3);
#pragma unroll
    for (int k = 0; k < K; ++k) {
      const int idx = tid + k * 256;
      if (idx < TOT4) {
        const int dv = idx / REAL4;           // compile-time divisor
        const int c = idx - dv * REAL4;
        const int v = min(zb0 + dv, n - 1);   // z-edge clamp (feeds unstored zo)
        int rel4 = ((v * n + yb0) * n) / 4 + c;   // chunk base %4==0 by construction
        rel4 = min(rel4, n3_4 - 1);           // volume-end clamp (garbage->unstored)
        st[k] = *reinterpret_cast<const float4*>(src + 4 * (long)rel4);
      }
    }
  };

  float acc[4][2][2] = {};                    // [zo][py][px]

  stage_load(0);                              // prologue

#pragma unroll 1
  for (int band = 0; band < 8; ++band) {
    if (band) __syncthreads();                // all waves done reading slab
#pragma unroll
    for (int k = 0; k < K; ++k) {             // commit staged regs -> LDS
      const int idx = tid + k * 256;
      if (idx < TOT4) *reinterpret_cast<float4*>(&slab[4 * idx]) = st[k];
    }
    __syncthreads();                          // slab visible to all
    if (band < 7) stage_load(band + 1);       // next band's loads fly under compute

    if (ty < WY) {
      const float* Gx = (band & 1) ? G1 : G0; // uniform scalar selects
      const float* Gy = (band & 2) ? G1 : G0;
      const float* Gz = (band & 4) ? G1 : G0;
#pragma unroll
      for (int dv = 0; dv < 5; ++dv) {
        // x-dots for the 4 source y-rows of this z-slice (row = ty+du, my=3-du)
        float d[4][2];
#pragma unroll
        for (int du = 0; du < 4; ++du) {
          const int base = dv * CH + (ty + du) * n + ux;
          const float r0 = slab[base], r1 = slab[base + 1];
          const float r2 = slab[base + 2], r3 = slab[base + 3];
          d[du][0] = r3 * Gx[0] + r2 * Gx[2] + r1 * Gx[4] + r0 * Gx[6];
          d[du][1] = r3 * Gx[1] + r2 * Gx[3] + r1 * Gx[5] + r0 * Gx[7];
        }
        // y-contract
        float ey[2][2];
#pragma unroll
        for (int py = 0; py < 2; ++py) {
#pragma unroll
          for (int px = 0; px < 2; ++px) {
            float s = d[0][px] * Gy[py + 6];
            s = fmaf(d[1][px], Gy[py + 4], s);
            s = fmaf(d[2][px], Gy[py + 2], s);
            s = fmaf(d[3][px], Gy[py + 0], s);
            ey[py][px] = s;
          }
        }
        // z-accumulate: slice dv feeds zo with mz=(zo>>1)+3-dv in [0,3]
#pragma unroll
        for (int zo = 0; zo < 4; ++zo) {
          const int mz = (zo >> 1) + 3 - dv;
          if (mz >= 0 && mz <= 3) {
            const float w = Gz[(zo & 1) + 2 * mz];
#pragma unroll
            for (int py = 0; py < 2; ++py)
#pragma unroll
              for (int px = 0; px < 2; ++px)
                acc[zo][py][px] = fmaf(ey[py][px], w, acc[zo][py][px]);
          }
        }
      }
    }
  }

  // stores
  const int uy = yb0 + ty;
  if (ty < WY && uy < H) {
    const long N3 = (long)N * N * N;
    float* obase = out + (long)b * N3 + 2 * ux;
#pragma unroll
    for (int zo = 0; zo < 4; ++zo) {
      if (zo >= 2 && !z1ok) continue;
      const int gz = 2 * zb0 + zo;
#pragma unroll
      for (int py = 0; py < 2; ++py) {
        const int gy = 2 * uy + py;
        float2 vv = make_float2(acc[zo][py][0], acc[zo][py][1]);
        *reinterpret_cast<float2*>(obase + ((long)gz * N + gy) * N) = vv;
      }
    }
  }
}

extern "C" void kernel_launch(void* const* d_in, const int* in_sizes, int n_in,
                              void* d_out, int out_size, void* d_ws, size_t ws_size,
                              hipStream_t stream) {
  // Identify inputs BY SIZE (element counts — confirmed in prior session):
  //   yl  (2,8,36^3)    =   746,496
  //   yh0 (2,8,7,66^3)  = 32,199,552
  //   yh1 (2,8,7,36^3)  =  5,225,472
  const float* yl  = nullptr;
  const float* yh0 = nullptr;
  const float* yh1 = nullptr;
  for (int i = 0; i < n_in; ++i) {
    if (in_sizes[i] == 746496)        yl  = (const float*)d_in[i];
    else if (in_sizes[i] == 32199552) yh0 = (const float*)d_in[i];
    else if (in_sizes[i] == 5225472)  yh1 = (const float*)d_in[i];
  }
  if (!yl || !yh0 || !yh1) {
    yl  = (const float*)d_in[0];
    yh0 = (const float*)d_in[1];
    yh1 = (const float*)d_in[2];
  }
  float* out = (float*)d_out;      // fp32 output (verified prior session)
  float* ll  = (float*)d_ws;       // (16,66^3) fp32 = 18.4 MB inter-level buffer

  // Level 1: (36 -> 66). H=33, WY=7 -> grid (17 zpairs, 5 ytiles, 16 vols).
  idwt3_lds<36, 7><<<dim3(17, 5, 16), 256, 0, stream>>>(yl, yh1, ll);

  // Level 2: (66 -> 126). H=63, WY=4 -> grid (32 zpairs, 16 ytiles, 16 vols).
  idwt3_lds<66, 4><<<dim3(32, 16, 16), 256, 0, stream>>>(ll, yh0, out);
}